// Round 3
// baseline (35309.097 us; speedup 1.0000x reference)
//
#include <hip/hip_runtime.h>
#include <math.h>

#define N_PTS 32768
#define M_SEL 8192
#define K_NBR 64
#define F_IN  64
#define H_MID 128
#define C_OUT 128
#define NCELL 512   // 8x8x8 grid
#define CAP   192   // per-centroid candidate cap

// ---------- helpers ----------

__device__ __forceinline__ int clamp8(int v) { return v < 0 ? 0 : (v > 7 ? 7 : v); }

__device__ __forceinline__ int cell_of(float px, float py, float pz) {
    int ix = clamp8((int)(px * 8.0f));
    int iy = clamp8((int)(py * 8.0f));
    int iz = clamp8((int)(pz * 8.0f));
    return (iz * 8 + iy) * 8 + ix;
}

// Bit-exact replica of numpy: ((dx*dx + dy*dy) + dz*dz), rn, no fma.
__device__ __forceinline__ float d2_exact(float ax, float ay, float az,
                                          float bx, float by, float bz) {
#pragma clang fp contract(off)
    float dx = ax - bx, dy = ay - by, dz = az - bz;
    return (dx * dx + dy * dy) + dz * dz;
}

// ---------- binning ----------

__global__ void bin_count_kernel(const float* __restrict__ pos, int* __restrict__ cnt) {
    int i = blockIdx.x * blockDim.x + threadIdx.x;
    if (i < N_PTS) {
        atomicAdd(&cnt[cell_of(pos[3*i], pos[3*i+1], pos[3*i+2])], 1);
    }
}

__global__ void scan_kernel(const int* __restrict__ cnt, int* __restrict__ start,
                            int* __restrict__ fill) {
    __shared__ int s[NCELL];
    int t = threadIdx.x;
    int v = cnt[t];
    s[t] = v;
    __syncthreads();
    for (int off = 1; off < NCELL; off <<= 1) {
        int add = (t >= off) ? s[t - off] : 0;
        __syncthreads();
        s[t] += add;
        __syncthreads();
    }
    int ex = s[t] - v;           // exclusive scan
    start[t] = ex;
    fill[t]  = ex;
    if (t == NCELL - 1) start[NCELL] = s[t];
}

// pq[slot] = (x, y, z, orig_index_as_float_bits) — one dwordx4 per point
__global__ void scatter_kernel(const float* __restrict__ pos, int* __restrict__ fill,
                               float4* __restrict__ pq) {
    int i = blockIdx.x * blockDim.x + threadIdx.x;
    if (i < N_PTS) {
        float px = pos[3*i], py = pos[3*i+1], pz = pos[3*i+2];
        int c = cell_of(px, py, pz);
        int slot = atomicAdd(&fill[c], 1);
        pq[slot] = make_float4(px, py, pz, __int_as_float(i));
    }
}

// ---------- FPS: single workgroup, static cell ownership, 2 barriers/iter ----------
// Wave w owns cells [32w, 32w+32). Per-cell (max,argbest,best-coords) in LDS,
// updated only by the owner wave -> no atomics, no flag list, no global load of
// the picked point's coords on the critical path.

__global__ __launch_bounds__(1024) void fps_kernel(
        const float4* __restrict__ pq, const int* __restrict__ cstart,
        const float* __restrict__ pos,
        float* __restrict__ mind, int* __restrict__ sel) {
    __shared__ float s_cmax[NCELL];
    __shared__ int   s_cbest[NCELL];
    __shared__ float s_cx[NCELL], s_cy[NCELL], s_cz[NCELL];
    __shared__ int   s_cs[NCELL + 1];
    __shared__ float s_pval[16], s_pcx[16], s_pcy[16], s_pcz[16];
    __shared__ int   s_pbest[16];
    __shared__ float s_px, s_py, s_pz;

    const int tid  = threadIdx.x;
    const int lane = tid & 63;
    const int wid  = tid >> 6;
    const int wbase = wid << 5;

    for (int i = tid; i < N_PTS; i += 1024) mind[i] = INFINITY;
    for (int i = tid; i < NCELL + 1; i += 1024) s_cs[i] = cstart[i];
    if (tid < NCELL) {
        // +inf for nonempty => every nonempty cell is "flagged" on iteration 1
        s_cmax[tid]  = (cstart[tid + 1] > cstart[tid]) ? INFINITY : -INFINITY;
        s_cbest[tid] = 0x7fffffff;
        s_cx[tid] = 0.0f; s_cy[tid] = 0.0f; s_cz[tid] = 0.0f;
    }
    if (tid == 0) { s_px = pos[0]; s_py = pos[1]; s_pz = pos[2]; sel[0] = 0; }
    __syncthreads();

    for (int m = 1; m < M_SEL; ++m) {
        const float px = s_px, py = s_py, pz = s_pz;

        // --- flags for this wave's own cells: bbox lower-bound < cell max ---
        bool flag = false;
        if (lane < 32) {
            const int c = wbase + lane;
            const float cm  = s_cmax[c];
            const float lox = (float)(c & 7)        * 0.125f;
            const float loy = (float)((c >> 3) & 7) * 0.125f;
            const float loz = (float)(c >> 6)       * 0.125f;
            float dx = fmaxf(fmaxf(lox - px, px - (lox + 0.125f)), 0.0f);
            float dy = fmaxf(fmaxf(loy - py, py - (loy + 0.125f)), 0.0f);
            float dz = fmaxf(fmaxf(loz - pz, pz - (loz + 0.125f)), 0.0f);
            float lb2 = dx * dx + dy * dy + dz * dz;
            flag = (lb2 * 0.999f < cm);      // conservative: flags strictly more
        }
        unsigned long long mask = __ballot(flag);

        // --- update flagged own cells; recompute their (max, argbest, coords) ---
        while (mask) {
            const int bit = __ffsll(mask) - 1;
            mask &= mask - 1;
            const int c  = wbase + bit;
            const int cs = s_cs[c], ce = s_cs[c + 1];
            float bv = -INFINITY, bx = 0.0f, by = 0.0f, bz = 0.0f;
            int   bo = 0x7fffffff;
            for (int j = cs + lane; j < ce; j += 64) {
                const float4 q  = pq[j];
                const float d2  = d2_exact(q.x, q.y, q.z, px, py, pz);
                const float old = mind[j];
                const float nv  = d2 < old ? d2 : old;
                if (nv < old) mind[j] = nv;          // fire-and-forget
                const int o = __float_as_int(q.w);
                if (nv > bv || (nv == bv && o < bo)) {
                    bv = nv; bo = o; bx = q.x; by = q.y; bz = q.z;
                }
            }
            const float lv = bv; const int lo = bo;
            for (int off = 1; off < 64; off <<= 1) {
                const float ov = __shfl_xor(bv, off);
                const int   oo = __shfl_xor(bo, off);
                if (ov > bv || (ov == bv && oo < bo)) { bv = ov; bo = oo; }
            }
            if (lv == bv && lo == bo) {              // unique winner lane writes
                s_cmax[c] = bv; s_cbest[c] = bo;
                s_cx[c] = bx; s_cy[c] = by; s_cz[c] = bz;
            }
        }

        // --- per-wave reduce over its 32 cells (incl. untouched ones) ---
        float wv = -INFINITY; int wo = 0x7fffffff;
        const int cown = wbase + lane;
        if (lane < 32) { wv = s_cmax[cown]; wo = s_cbest[cown]; }
        const float wlv = wv; const int wlo = wo;
        for (int off = 1; off < 64; off <<= 1) {
            const float ov = __shfl_xor(wv, off);
            const int   oo = __shfl_xor(wo, off);
            if (ov > wv || (ov == wv && oo < wo)) { wv = ov; wo = oo; }
        }
        if (lane < 32 && wlv == wv && wlo == wo) {
            s_pval[wid] = wv; s_pbest[wid] = wo;
            s_pcx[wid] = s_cx[cown]; s_pcy[wid] = s_cy[cown]; s_pcz[wid] = s_cz[cown];
        }
        __syncthreads();

        // --- wave0: final reduce over 16 wave partials, publish new p ---
        if (wid == 0) {
            float fv = -INFINITY; int fo = 0x7fffffff;
            if (lane < 16) { fv = s_pval[lane]; fo = s_pbest[lane]; }
            const float flv = fv; const int flo = fo;
            for (int off = 1; off < 16; off <<= 1) {
                const float ov = __shfl_xor(fv, off);
                const int   oo = __shfl_xor(fo, off);
                if (ov > fv || (ov == fv && oo < fo)) { fv = ov; fo = oo; }
            }
            if (lane < 16 && flv == fv && flo == fo) {
                sel[m] = fo;                          // fire-and-forget
                s_px = s_pcx[lane]; s_py = s_pcy[lane]; s_pz = s_pcz[lane];
            }
        }
        __syncthreads();
    }
}

// ---------- ball query: up-to-64 nearest in-radius (one wave / centroid) ----------

__global__ __launch_bounds__(256) void ballq_kernel(
        const float* __restrict__ pos,
        const float4* __restrict__ pq,
        const int* __restrict__ cstart, const int* __restrict__ sel,
        int* __restrict__ nbr, int* __restrict__ ncnt) {
    __shared__ float s_d2[4][CAP];
    __shared__ int   s_o[4][CAP];
    __shared__ int   s_cnt[4];

    const int wid  = threadIdx.x >> 6;
    const int lane = threadIdx.x & 63;
    const int m = blockIdx.x * 4 + wid;

    if (lane == 0) s_cnt[wid] = 0;
    __syncthreads();

    int sidx = sel[m];
    float cx = pos[3*sidx], cy = pos[3*sidx+1], cz = pos[3*sidx+2];
    int ix = clamp8((int)(cx * 8.0f));
    int iy = clamp8((int)(cy * 8.0f));
    int iz = clamp8((int)(cz * 8.0f));
    const float r2 = (float)(0.08 * 0.08);

    for (int dz = -1; dz <= 1; ++dz) {
        int z = iz + dz; if (z < 0 || z > 7) continue;
        for (int dy = -1; dy <= 1; ++dy) {
            int y = iy + dy; if (y < 0 || y > 7) continue;
            for (int dx = -1; dx <= 1; ++dx) {
                int xq = ix + dx; if (xq < 0 || xq > 7) continue;
                int c = (z * 8 + y) * 8 + xq;
                int cs = cstart[c], ce = cstart[c + 1];
                for (int j = cs + lane; j < ce; j += 64) {
                    float4 q = pq[j];
                    float d2 = d2_exact(cx, cy, cz, q.x, q.y, q.z);
                    if (d2 <= r2) {
                        int slot = atomicAdd(&s_cnt[wid], 1);
                        if (slot < CAP) { s_d2[wid][slot] = d2; s_o[wid][slot] = __float_as_int(q.w); }
                    }
                }
            }
        }
    }
    __syncthreads();

    int cnt = s_cnt[wid];
    if (cnt > CAP) cnt = CAP;
    if (cnt <= K_NBR) {
        if (lane < cnt) nbr[m * K_NBR + lane] = s_o[wid][lane];
        if (lane == 0) ncnt[m] = cnt;
    } else {
        // exact (d2, orig-index) lexicographic rank -> keep 64 nearest (matches top_k)
        for (int i = lane; i < cnt; i += 64) {
            float d2 = s_d2[wid][i];
            int   o  = s_o[wid][i];
            int rank = 0;
            for (int j = 0; j < cnt; ++j) {
                float dj = s_d2[wid][j];
                int   oj = s_o[wid][j];
                rank += (dj < d2 || (dj == d2 && oj < o)) ? 1 : 0;
            }
            if (rank < K_NBR) nbr[m * K_NBR + rank] = o;
        }
        if (lane == 0) ncnt[m] = K_NBR;
    }
}

// ---------- PointConv MLP + masked max-pool (fp32, one block / centroid) ----------

__global__ __launch_bounds__(256) void mlp_kernel(
        const float* __restrict__ x, const float* __restrict__ pos,
        const float* __restrict__ W1, const float* __restrict__ b1,
        const float* __restrict__ W2, const float* __restrict__ b2,
        const int* __restrict__ sel, const int* __restrict__ nbr,
        const int* __restrict__ ncnt, float* __restrict__ out) {
    __shared__ __align__(16) float feat[64][68];   // 67 used + pad
    __shared__ __align__(16) float h[64][H_MID];
    __shared__ float part[2][H_MID];

    const int m = blockIdx.x;
    const int tid = threadIdx.x;
    const int cnt = ncnt[m];
    const int s = sel[m];
    float cx = pos[3*s], cy = pos[3*s+1], cz = pos[3*s+2];

    for (int i = tid; i < 64 * 68; i += 256) ((float*)feat)[i] = 0.0f;
    __syncthreads();

    for (int i = tid; i < cnt * F_IN; i += 256) {
        int k = i >> 6, f = i & 63;
        int j = nbr[m * K_NBR + k];
        feat[k][f] = x[(size_t)j * F_IN + f];
    }
    if (tid < 64 && tid < cnt) {
        int j = nbr[m * K_NBR + tid];
        feat[tid][64] = pos[3*j]     - cx;
        feat[tid][65] = pos[3*j + 1] - cy;
        feat[tid][66] = pos[3*j + 2] - cz;
    }
    __syncthreads();

    const int c = tid & 127;
    const int half = tid >> 7;

    for (int k = half; k < 64; k += 2) {
        float acc = b1[c];
        const float4* fr = (const float4*)&feat[k][0];
#pragma unroll
        for (int f4 = 0; f4 < 16; ++f4) {
            float4 fv = fr[f4];
            int fb = f4 * 4;
            acc = fmaf(fv.x, W1[(fb    ) * H_MID + c], acc);
            acc = fmaf(fv.y, W1[(fb + 1) * H_MID + c], acc);
            acc = fmaf(fv.z, W1[(fb + 2) * H_MID + c], acc);
            acc = fmaf(fv.w, W1[(fb + 3) * H_MID + c], acc);
        }
        acc = fmaf(feat[k][64], W1[64 * H_MID + c], acc);
        acc = fmaf(feat[k][65], W1[65 * H_MID + c], acc);
        acc = fmaf(feat[k][66], W1[66 * H_MID + c], acc);
        h[k][c] = fmaxf(acc, 0.0f);
    }
    __syncthreads();

    float best = -INFINITY;
    for (int k = half; k < cnt; k += 2) {
        float acc = 0.0f;
        const float4* hr = (const float4*)&h[k][0];
#pragma unroll
        for (int q = 0; q < 32; ++q) {
            float4 hv = hr[q];
            int hb = q * 4;
            acc = fmaf(hv.x, W2[(hb    ) * C_OUT + c], acc);
            acc = fmaf(hv.y, W2[(hb + 1) * C_OUT + c], acc);
            acc = fmaf(hv.z, W2[(hb + 2) * C_OUT + c], acc);
            acc = fmaf(hv.w, W2[(hb + 3) * C_OUT + c], acc);
        }
        best = fmaxf(best, acc);
    }
    part[half][c] = best;
    __syncthreads();
    if (tid < 128) {
        out[(size_t)m * C_OUT + tid] = fmaxf(part[0][tid], part[1][tid]) + b2[tid];
    }
}

// ---------- outputs 2 & 3 ----------

__global__ void tail_kernel(const float* __restrict__ pos, const int* __restrict__ sel,
                            float* __restrict__ out_selpos, float* __restrict__ out_batch) {
    int i = blockIdx.x * blockDim.x + threadIdx.x;
    if (i < M_SEL) {
        int s = sel[i];
        out_selpos[3*i]     = pos[3*s];
        out_selpos[3*i + 1] = pos[3*s + 1];
        out_selpos[3*i + 2] = pos[3*s + 2];
        out_batch[i] = 0.0f;
    }
}

// ---------- launch ----------

extern "C" void kernel_launch(void* const* d_in, const int* in_sizes, int n_in,
                              void* d_out, int out_size, void* d_ws, size_t ws_size,
                              hipStream_t stream) {
    const float* x   = (const float*)d_in[0];
    const float* pos = (const float*)d_in[1];
    // d_in[2] = batch (int64, all zeros) — unused
    const float* W1 = (const float*)d_in[3];
    const float* b1 = (const float*)d_in[4];
    const float* W2 = (const float*)d_in[5];
    const float* b2 = (const float*)d_in[6];

    float* out        = (float*)d_out;
    float* out_selpos = out + (size_t)M_SEL * C_OUT;
    float* out_batch  = out_selpos + (size_t)M_SEL * 3;

    char* ws = (char*)d_ws;
    size_t off = 0;
    auto alloc = [&](size_t bytes) -> void* {
        void* p = ws + off;
        off = (off + bytes + 255) & ~(size_t)255;
        return p;
    };
    int*    cnt    = (int*)alloc(NCELL * 4);
    int*    cstart = (int*)alloc((NCELL + 1) * 4);
    int*    cfill  = (int*)alloc(NCELL * 4);
    float4* pq     = (float4*)alloc((size_t)N_PTS * 16);
    float*  mind   = (float*)alloc(N_PTS * 4);
    int*    sel    = (int*)alloc(M_SEL * 4);
    int*    nbr    = (int*)alloc((size_t)M_SEL * K_NBR * 4);
    int*    ncnt   = (int*)alloc(M_SEL * 4);
    (void)ws_size; (void)in_sizes; (void)n_in; (void)out_size;

    (void)hipMemsetAsync(cnt, 0, NCELL * 4, stream);
    bin_count_kernel<<<N_PTS / 256, 256, 0, stream>>>(pos, cnt);
    scan_kernel<<<1, NCELL, 0, stream>>>(cnt, cstart, cfill);
    scatter_kernel<<<N_PTS / 256, 256, 0, stream>>>(pos, cfill, pq);
    fps_kernel<<<1, 1024, 0, stream>>>(pq, cstart, pos, mind, sel);
    ballq_kernel<<<M_SEL / 4, 256, 0, stream>>>(pos, pq, cstart, sel, nbr, ncnt);
    mlp_kernel<<<M_SEL, 256, 0, stream>>>(x, pos, W1, b1, W2, b2, sel, nbr, ncnt, out);
    tail_kernel<<<(M_SEL + 255) / 256, 256, 0, stream>>>(pos, sel, out_selpos, out_batch);
}